// Round 4
// baseline (371.018 us; speedup 1.0000x reference)
//
#include <hip/hip_runtime.h>

typedef unsigned short u16;
typedef unsigned int u32;
typedef __attribute__((ext_vector_type(4))) float f32x4;
typedef __attribute__((ext_vector_type(8))) short bf16x8;
typedef __attribute__((ext_vector_type(4))) unsigned short u16x4;
typedef __attribute__((ext_vector_type(8))) unsigned short u16x8;

#define NH 16
#define HD 128
#define TT 256
#define CDIM 2048

__device__ __forceinline__ u16 f2bf(float f) {
  u32 u = __float_as_uint(f);
  u = (u + 0x7fffu + ((u >> 16) & 1u)) >> 16;
  return (u16)u;
}
__device__ __forceinline__ float bf2f(u16 h) {
  return __uint_as_float(((u32)h) << 16);
}
__device__ __forceinline__ void gload_lds16(const u16* g, u16* l) {
  __builtin_amdgcn_global_load_lds((__attribute__((address_space(1))) void*)g,
                                   (__attribute__((address_space(3))) void*)l, 16, 0, 0);
}

#define BAR() __builtin_amdgcn_s_barrier()
#define SCB() __builtin_amdgcn_sched_barrier(0)
#define WL0()                                          \
  {                                                    \
    asm volatile("s_waitcnt lgkmcnt(0)" ::: "memory"); \
    SCB();                                             \
  }
#define WV6()                                         \
  {                                                   \
    asm volatile("s_waitcnt vmcnt(6)" ::: "memory");  \
    SCB();                                            \
  }
#define WV0()                                         \
  {                                                   \
    asm volatile("s_waitcnt vmcnt(0)" ::: "memory");  \
    SCB();                                            \
  }
#define P1() __builtin_amdgcn_s_setprio(1)
#define P0() __builtin_amdgcn_s_setprio(0)

// ---------------- convert f32 -> bf16, 8 elems/thread ----------------
__global__ __launch_bounds__(256) void cvt_bf16_kernel(const float* __restrict__ src,
                                                       u16* __restrict__ dst, int n8) {
  int i = blockIdx.x * 256 + threadIdx.x;
  if (i >= n8) return;
  const float4* s4 = (const float4*)src;
  float4 a = s4[i * 2];
  float4 b = s4[i * 2 + 1];
  u16x8 r;
  r[0] = f2bf(a.x); r[1] = f2bf(a.y); r[2] = f2bf(a.z); r[3] = f2bf(a.w);
  r[4] = f2bf(b.x); r[5] = f2bf(b.y); r[6] = f2bf(b.z); r[7] = f2bf(b.w);
  *(u16x8*)(dst + (long)i * 8) = r;
}

// all four weight matrices in one launch
__global__ __launch_bounds__(256) void cvt_w_kernel(const float* __restrict__ wq,
                                                    const float* __restrict__ wk,
                                                    const float* __restrict__ wv,
                                                    const float* __restrict__ wo,
                                                    u16* __restrict__ wqkv,
                                                    u16* __restrict__ wobf) {
  int i = blockIdx.x * 256 + threadIdx.x;
  int seg = i >> 19;
  int r8 = i & 524287;
  const float* s = (seg == 0) ? wq : (seg == 1) ? wk : (seg == 2) ? wv : wo;
  u16* d = (seg == 3) ? wobf : (wqkv + (long)seg * 4194304);
  const float4* s4 = (const float4*)s;
  float4 a = s4[r8 * 2];
  float4 b = s4[r8 * 2 + 1];
  u16x8 r;
  r[0] = f2bf(a.x); r[1] = f2bf(a.y); r[2] = f2bf(a.z); r[3] = f2bf(a.w);
  r[4] = f2bf(b.x); r[5] = f2bf(b.y); r[6] = f2bf(b.z); r[7] = f2bf(b.w);
  *(u16x8*)(d + (long)r8 * 8) = r;
}

// ---------------- rope tables: [256][64] cos,sin ----------------
__global__ void rope_tables_kernel(float* __restrict__ cosT, float* __restrict__ sinT) {
  int i = blockIdx.x * 256 + threadIdx.x;  // 16384
  int t = i >> 6, d = i & 63;
  float inv = __expf(-(float)d * (9.210340371976184f / 64.0f));
  float a = (float)t * inv;
  cosT[i] = cosf(a);
  sinT[i] = sinf(a);
}

// ---------------- rope apply in-place on q (scaled) and k ----------------
__global__ __launch_bounds__(256) void rope_apply_kernel(u16* __restrict__ q, u16* __restrict__ k,
                                                         const float* __restrict__ cosT,
                                                         const float* __restrict__ sinT) {
  int idx = blockIdx.x * 256 + threadIdx.x;  // 2 * 2097152
  u16* base;
  float sc;
  int i;
  if (idx < 2097152) { base = q; sc = 0.08838834764831845f; i = idx; }
  else               { base = k; sc = 1.0f;                 i = idx - 2097152; }
  int row = i >> 4, d0 = (i & 15) * 4;
  int t = row & 255;
  u16* p1 = base + (long)row * HD + d0;
  u16* p2 = p1 + 64;
  u16x4 x1 = *(u16x4*)p1;
  u16x4 x2 = *(u16x4*)p2;
  float4 c4 = *(const float4*)(cosT + t * 64 + d0);
  float4 s4 = *(const float4*)(sinT + t * 64 + d0);
  float a0 = bf2f(x1[0]), a1 = bf2f(x1[1]), a2 = bf2f(x1[2]), a3 = bf2f(x1[3]);
  float b0 = bf2f(x2[0]), b1 = bf2f(x2[1]), b2 = bf2f(x2[2]), b3 = bf2f(x2[3]);
  u16x4 o1, o2;
  o1[0] = f2bf((a0 * c4.x - b0 * s4.x) * sc);
  o1[1] = f2bf((a1 * c4.y - b1 * s4.y) * sc);
  o1[2] = f2bf((a2 * c4.z - b2 * s4.z) * sc);
  o1[3] = f2bf((a3 * c4.w - b3 * s4.w) * sc);
  o2[0] = f2bf((b0 * c4.x + a0 * s4.x) * sc);
  o2[1] = f2bf((b1 * c4.y + a1 * s4.y) * sc);
  o2[2] = f2bf((b2 * c4.z + a2 * s4.z) * sc);
  o2[3] = f2bf((b3 * c4.w + a3 * s4.w) * sc);
  *(u16x4*)p1 = o1;
  *(u16x4*)p2 = o2;
}

// ---------------- 256x256 8-phase GEMM  C = A * B^T ----------------
// 512 threads = 8 waves. Wave output = split sub-tiles: rows {mh*128+(wid>>2)*64+[0,64)},
// cols {nh*128+(wid&3)*32+[0,32)} -- every LDA_(mh)/LDB_(nh) confined to one stage-half.
// 1 stage/phase rotation, vmcnt(6) at p4/p8 (3 half-tiles in flight), XCD swizzle.
#define MM(MH, NHh)                                                             \
  _Pragma("unroll") for (int ks = 0; ks < 2; ++ks)                              \
  _Pragma("unroll") for (int f = 0; f < 4; ++f)                                 \
  _Pragma("unroll") for (int fn = 0; fn < 2; ++fn)                              \
      acc[(MH)*4 + f][(NHh)*2 + fn] = __builtin_amdgcn_mfma_f32_16x16x32_bf16(  \
          fa[f][ks], fb[fn][ks], acc[(MH)*4 + f][(NHh)*2 + fn], 0, 0, 0);

template <int MODE>
__global__ __launch_bounds__(512, 2) void gemm256(const u16* __restrict__ A,
                                                  const u16* __restrict__ Bt,
                                                  float* __restrict__ Cf, u16* __restrict__ Qo,
                                                  u16* __restrict__ Ko, u16* __restrict__ Vo,
                                                  int M, int N, int K, int GX) {
  __shared__ u16 lds[65536];  // [buf0.A][buf0.B][buf1.A][buf1.B], 16384 u16 each
  // bijective XCD swizzle (gridDim.x % 8 == 0)
  const int nwg = gridDim.x, qx = nwg >> 3;
  const int wg = ((int)blockIdx.x & 7) * qx + ((int)blockIdx.x >> 3);
  const int bn = wg % GX, bm = wg / GX;
  const int tid = threadIdx.x, wid = tid >> 6, lane = tid & 63;
  const int lr = lane & 15, lg = lane >> 4;
  const int wrow = (wid >> 2) * 64;  // within each 128-row M half
  const int wcol = (wid & 3) * 32;   // within each 128-col N half
  const int NT = K >> 6;
  const u16* Ag = A + (long)(bm * 256) * K;
  const u16* Bg = Bt + (long)(bn * 256) * K;

  // stage one half-tile (128 rows x 64 cols). LDS dest linear, source col pre-swizzled.
  auto STG = [&](int matbase, int h, const u16* Gp, int kt) {
    if (kt > NT - 1) kt = NT - 1;
#pragma unroll
    for (int i_ = 0; i_ < 2; ++i_) {
      int s = i_ * 512 + tid;
      int r = h * 128 + (s >> 3);
      int cs = (s & 7) ^ (r & 7);
      gload_lds16(Gp + (long)r * K + kt * 64 + cs * 8, &lds[matbase + h * 8192 + s * 8]);
    }
  };

  bf16x8 fa[4][2], fb[2][2];
  auto LDA_ = [&](int base, int mh) {
#pragma unroll
    for (int f = 0; f < 4; ++f)
#pragma unroll
      for (int ks = 0; ks < 2; ++ks) {
        int r = wrow + f * 16 + lr;  // 0..127 within half
        fa[f][ks] = *(const bf16x8*)&lds[base + mh * 8192 + r * 64 + (((ks * 4 + lg) ^ (r & 7))) * 8];
      }
  };
  auto LDB_ = [&](int base, int nh) {
#pragma unroll
    for (int fn = 0; fn < 2; ++fn)
#pragma unroll
      for (int ks = 0; ks < 2; ++ks) {
        int r = wcol + fn * 16 + lr;  // 0..127 within half
        fb[fn][ks] = *(const bf16x8*)&lds[base + nh * 8192 + r * 64 + (((ks * 4 + lg) ^ (r & 7))) * 8];
      }
  };

  const f32x4 zero = {0.f, 0.f, 0.f, 0.f};
  f32x4 acc[8][4];
#pragma unroll
  for (int a = 0; a < 8; ++a)
#pragma unroll
    for (int b = 0; b < 4; ++b) acc[a][b] = zero;

  // prologue: t0 fully (A0,B0,B1,A1), t1 partial (A0,B1,A1); B0(t1) staged at first p1
  STG(0, 0, Ag, 0);
  STG(16384, 0, Bg, 0);
  STG(16384, 1, Bg, 0);
  STG(0, 1, Ag, 0);
  STG(32768, 0, Ag, 1);
  STG(49152, 1, Bg, 1);
  STG(32768, 1, Ag, 1);
  WV6();  // t0's 4 stages drained; t1's 3 in flight
  BAR();

  const int J = NT >> 1;
  for (int j = 0; j < J; ++j) {
    const int t1 = 2 * j + 1, tn0 = 2 * j + 2, tn1 = 2 * j + 3;
    // p1: Q(0,0) t0; stage buf1.B0 <- t1
    LDA_(0, 0); LDB_(16384, 0);
    STG(49152, 0, Bg, t1);
    BAR(); WL0();
    P1(); MM(0, 0) P0();
    BAR();
    // p2: Q(0,1); stage buf0.A0 <- tn0
    LDB_(16384, 1);
    STG(0, 0, Ag, tn0);
    BAR(); WL0();
    P1(); MM(0, 1) P0();
    BAR();
    // p3: Q(1,1); stage buf0.B1 <- tn0
    LDA_(0, 1);
    STG(16384, 1, Bg, tn0);
    BAR(); WL0();
    P1(); MM(1, 1) P0();
    BAR();
    // p4: Q(1,0); stage buf0.A1 <- tn0; counted wait -> buf1 (t1) ready
    LDB_(16384, 0);
    STG(0, 1, Ag, tn0);
    BAR(); WL0();
    P1(); MM(1, 0) P0();
    WV6();
    BAR();
    // p5: Q(0,0) t1; stage buf0.B0 <- tn0
    LDA_(32768, 0); LDB_(49152, 0);
    STG(16384, 0, Bg, tn0);
    BAR(); WL0();
    P1(); MM(0, 0) P0();
    BAR();
    // p6: Q(0,1); stage buf1.A0 <- tn1
    LDB_(49152, 1);
    STG(32768, 0, Ag, tn1);
    BAR(); WL0();
    P1(); MM(0, 1) P0();
    BAR();
    // p7: Q(1,1); stage buf1.B1 <- tn1
    LDA_(32768, 1);
    STG(49152, 1, Bg, tn1);
    BAR(); WL0();
    P1(); MM(1, 1) P0();
    BAR();
    // p8: Q(1,0); stage buf1.A1 <- tn1; counted wait -> buf0 (tn0) ready
    LDB_(49152, 0);
    STG(32768, 1, Ag, tn1);
    BAR(); WL0();
    P1(); MM(1, 0) P0();
    WV6();
    BAR();
  }
  WV0();  // drain in-flight LDS-DMA before block exit (next block reuses this LDS)

  // epilogue: m = bm*256 + mh*128 + wrow + f*16 + lg*4 + r
  //           n = bn*256 + nh*128 + wcol + fn*16 + lr
  if (MODE == 0) {
#pragma unroll
    for (int am = 0; am < 8; ++am)
#pragma unroll
      for (int an = 0; an < 4; ++an)
#pragma unroll
        for (int r = 0; r < 4; ++r) {
          int m = bm * 256 + (am >> 2) * 128 + wrow + (am & 3) * 16 + lg * 4 + r;
          int n = bn * 256 + (an >> 1) * 128 + wcol + (an & 1) * 16 + lr;
          Cf[(long)m * N + n] = acc[am][an][r];
        }
  } else {
#pragma unroll
    for (int am = 0; am < 8; ++am)
#pragma unroll
      for (int an = 0; an < 4; ++an)
#pragma unroll
        for (int r = 0; r < 4; ++r) {
          int m = bm * 256 + (am >> 2) * 128 + wrow + (am & 3) * 16 + lg * 4 + r;
          int n = bn * 256 + (an >> 1) * 128 + wcol + (an & 1) * 16 + lr;
          int mat = n >> 11, head = (n >> 7) & 15, d = n & 127;
          u16* dst = (mat == 0) ? Qo : ((mat == 1) ? Ko : Vo);
          int b = m >> 8, t = m & 255;
          dst[(((long)(b * NH + head)) * TT + t) * HD + d] = f2bf(acc[am][an][r]);
        }
  }
}

// ---------------- fused causal attention ----------------
__global__ __launch_bounds__(256, 2) void attn_kernel(const u16* __restrict__ Qb,
                                                      const u16* __restrict__ Kb,
                                                      const u16* __restrict__ Vb,
                                                      u16* __restrict__ Ob) {
  __shared__ u16 Ks[64][136];
  __shared__ u16 Vt[128][72];
  __shared__ u16 Ps[4][32][72];
  const int bid = blockIdx.x;
  const int qb = bid & 1, h = (bid >> 1) & 15, b = bid >> 5;
  const int tid = threadIdx.x, wid = tid >> 6, lane = tid & 63;
  const int lr = lane & 15, lg = lane >> 4;
  const u16* qh = Qb + ((long)(b * NH + h)) * TT * HD;
  const u16* kh = Kb + ((long)(b * NH + h)) * TT * HD;
  const u16* vh = Vb + ((long)(b * NH + h)) * TT * HD;
  const int q0 = qb * 128 + wid * 32;

  bf16x8 qf[2][4];
#pragma unroll
  for (int fq = 0; fq < 2; ++fq)
#pragma unroll
    for (int ds = 0; ds < 4; ++ds)
      qf[fq][ds] = *(const bf16x8*)(qh + (long)(q0 + fq * 16 + lr) * HD + ds * 32 + lg * 8);

  const f32x4 zero = {0.f, 0.f, 0.f, 0.f};
  f32x4 oacc[2][8];
#pragma unroll
  for (int fq = 0; fq < 2; ++fq)
#pragma unroll
    for (int fd = 0; fd < 8; ++fd) oacc[fq][fd] = zero;
  float mrow[2][4], lrow[2][4];
#pragma unroll
  for (int fq = 0; fq < 2; ++fq)
#pragma unroll
    for (int r = 0; r < 4; ++r) { mrow[fq][r] = -1e30f; lrow[fq][r] = 0.f; }

  const int nch = (qb == 0) ? 2 : 4;
  for (int kc = 0; kc < nch; ++kc) {
    __syncthreads();
#pragma unroll
    for (int it = 0; it < 4; ++it) {
      int task = it * 256 + tid;
      int r = task >> 4, sg = task & 15;
      u16x8 v = *(const u16x8*)(kh + (long)(kc * 64 + r) * HD + sg * 8);
      *(u16x8*)(&Ks[r][sg * 8]) = v;
    }
#pragma unroll
    for (int it = 0; it < 4; ++it) {
      int task = it * 256 + tid;
      int r = task >> 4, d0 = (task & 15) * 8;
      u16x8 v = *(const u16x8*)(vh + (long)(kc * 64 + r) * HD + d0);
#pragma unroll
      for (int j = 0; j < 8; ++j) Vt[d0 + j][r] = v[j];
    }
    __syncthreads();

    f32x4 sacc[2][4];
#pragma unroll
    for (int fq = 0; fq < 2; ++fq)
#pragma unroll
      for (int fk = 0; fk < 4; ++fk) sacc[fq][fk] = zero;
#pragma unroll
    for (int ds = 0; ds < 4; ++ds) {
      bf16x8 kf[4];
#pragma unroll
      for (int fk = 0; fk < 4; ++fk)
        kf[fk] = *(const bf16x8*)(&Ks[fk * 16 + lr][ds * 32 + lg * 8]);
#pragma unroll
      for (int fq = 0; fq < 2; ++fq)
#pragma unroll
        for (int fk = 0; fk < 4; ++fk)
          sacc[fq][fk] =
              __builtin_amdgcn_mfma_f32_16x16x32_bf16(qf[fq][ds], kf[fk], sacc[fq][fk], 0, 0, 0);
    }

#pragma unroll
    for (int fq = 0; fq < 2; ++fq) {
      float mnew[4], alpha[4], psum[4];
#pragma unroll
      for (int r = 0; r < 4; ++r) {
        int qrow = q0 + fq * 16 + lg * 4 + r;
        float cmax = -1e30f;
#pragma unroll
        for (int fk = 0; fk < 4; ++fk) {
          int kcol = kc * 64 + fk * 16 + lr;
          float s = sacc[fq][fk][r];
          if (kcol > qrow) s = -1e30f;
          sacc[fq][fk][r] = s;
          cmax = fmaxf(cmax, s);
        }
#pragma unroll
        for (int off = 1; off < 16; off <<= 1) cmax = fmaxf(cmax, __shfl_xor(cmax, off));
        mnew[r] = fmaxf(mrow[fq][r], cmax);
        alpha[r] = __expf(mrow[fq][r] - mnew[r]);
        mrow[fq][r] = mnew[r];
        psum[r] = 0.f;
      }
#pragma unroll
      for (int fk = 0; fk < 4; ++fk)
#pragma unroll
        for (int r = 0; r < 4; ++r) {
          float p = __expf(sacc[fq][fk][r] - mnew[r]);
          psum[r] += p;
          Ps[wid][fq * 16 + lg * 4 + r][fk * 16 + lr] = f2bf(p);
        }
#pragma unroll
      for (int r = 0; r < 4; ++r) {
        float ps = psum[r];
#pragma unroll
        for (int off = 1; off < 16; off <<= 1) ps += __shfl_xor(ps, off);
        lrow[fq][r] = lrow[fq][r] * alpha[r] + ps;
#pragma unroll
        for (int fd = 0; fd < 8; ++fd) oacc[fq][fd][r] *= alpha[r];
      }
    }

#pragma unroll
    for (int ks = 0; ks < 2; ++ks) {
      bf16x8 pf0 = *(const bf16x8*)(&Ps[wid][lr][ks * 32 + lg * 8]);
      bf16x8 pf1 = *(const bf16x8*)(&Ps[wid][16 + lr][ks * 32 + lg * 8]);
#pragma unroll
      for (int fd = 0; fd < 8; ++fd) {
        bf16x8 vf = *(const bf16x8*)(&Vt[fd * 16 + lr][ks * 32 + lg * 8]);
        oacc[0][fd] = __builtin_amdgcn_mfma_f32_16x16x32_bf16(pf0, vf, oacc[0][fd], 0, 0, 0);
        oacc[1][fd] = __builtin_amdgcn_mfma_f32_16x16x32_bf16(pf1, vf, oacc[1][fd], 0, 0, 0);
      }
    }
  }

#pragma unroll
  for (int fq = 0; fq < 2; ++fq)
#pragma unroll
    for (int r = 0; r < 4; ++r) {
      float inv = 1.0f / lrow[fq][r];
      int t = q0 + fq * 16 + lg * 4 + r;
      u16* od = Ob + ((long)(b * TT + t)) * CDIM + h * HD;
#pragma unroll
      for (int fd = 0; fd < 8; ++fd) od[fd * 16 + lr] = f2bf(oacc[fq][fd][r] * inv);
    }
}

extern "C" void kernel_launch(void* const* d_in, const int* in_sizes, int n_in, void* d_out,
                              int out_size, void* d_ws, size_t ws_size, hipStream_t stream) {
  const float* x = (const float*)d_in[0];
  const float* wq = (const float*)d_in[2];
  const float* wk = (const float*)d_in[3];
  const float* wv = (const float*)d_in[4];
  const float* wo = (const float*)d_in[5];

  char* ws = (char*)d_ws;
  u16* xbf = (u16*)(ws);                   // 32 MB; later reused as attn-out [b][t][c]
  u16* wqkv = (u16*)(ws + 33554432);       // 24 MB  [6144][2048]
  u16* wobf = (u16*)(ws + 58720256);       // 8 MB
  u16* qbf = (u16*)(ws + 67108864);        // 32 MB  [b][h][t][d]
  u16* kbf = (u16*)(ws + 100663296);       // 32 MB
  u16* vbf = (u16*)(ws + 134217728);       // 32 MB
  float* cosT = (float*)(ws + 167772160);  // 64 KB
  float* sinT = (float*)(ws + 167837696);  // 64 KB

  cvt_bf16_kernel<<<8192, 256, 0, stream>>>(x, xbf, 2097152);
  cvt_w_kernel<<<8192, 256, 0, stream>>>(wq, wk, wv, wo, wqkv, wobf);
  rope_tables_kernel<<<64, 256, 0, stream>>>(cosT, sinT);

  gemm256<1><<<768, 512, 0, stream>>>(xbf, wqkv, nullptr, qbf, kbf, vbf, 8192, 6144, 2048, 24);
  rope_apply_kernel<<<16384, 256, 0, stream>>>(qbf, kbf, cosT, sinT);
  attn_kernel<<<1024, 256, 0, stream>>>(qbf, kbf, vbf, xbf);
  gemm256<0><<<256, 512, 0, stream>>>(xbf, wobf, (float*)d_out, nullptr, nullptr, nullptr, 8192,
                                      2048, 2048, 8);
}

// Round 5
// 354.303 us; speedup vs baseline: 1.0472x; 1.0472x over previous
//
#include <hip/hip_runtime.h>

typedef unsigned short u16;
typedef unsigned int u32;
typedef __attribute__((ext_vector_type(4))) float f32x4;
typedef __attribute__((ext_vector_type(8))) short bf16x8;
typedef __attribute__((ext_vector_type(4))) unsigned short u16x4;
typedef __attribute__((ext_vector_type(8))) unsigned short u16x8;

#define NH 16
#define HD 128
#define TT 256
#define CDIM 2048

__device__ __forceinline__ u16 f2bf(float f) {
  u32 u = __float_as_uint(f);
  u = (u + 0x7fffu + ((u >> 16) & 1u)) >> 16;
  return (u16)u;
}
__device__ __forceinline__ float bf2f(u16 h) {
  return __uint_as_float(((u32)h) << 16);
}
__device__ __forceinline__ void gload_lds16(const u16* g, u16* l) {
  __builtin_amdgcn_global_load_lds((__attribute__((address_space(1))) void*)g,
                                   (__attribute__((address_space(3))) void*)l, 16, 0, 0);
}

#define BAR() __builtin_amdgcn_s_barrier()
#define SCB() __builtin_amdgcn_sched_barrier(0)
#define WL0()                                          \
  {                                                    \
    asm volatile("s_waitcnt lgkmcnt(0)" ::: "memory"); \
    SCB();                                             \
  }
#define WV6()                                         \
  {                                                   \
    asm volatile("s_waitcnt vmcnt(6)" ::: "memory");  \
    SCB();                                            \
  }
#define WV0()                                         \
  {                                                   \
    asm volatile("s_waitcnt vmcnt(0)" ::: "memory");  \
    SCB();                                            \
  }
#define P1() __builtin_amdgcn_s_setprio(1)
#define P0() __builtin_amdgcn_s_setprio(0)

// ---------------- convert f32 -> bf16, 8 elems/thread ----------------
__global__ __launch_bounds__(256) void cvt_bf16_kernel(const float* __restrict__ src,
                                                       u16* __restrict__ dst, int n8) {
  int i = blockIdx.x * 256 + threadIdx.x;
  if (i >= n8) return;
  const float4* s4 = (const float4*)src;
  float4 a = s4[i * 2];
  float4 b = s4[i * 2 + 1];
  u16x8 r;
  r[0] = f2bf(a.x); r[1] = f2bf(a.y); r[2] = f2bf(a.z); r[3] = f2bf(a.w);
  r[4] = f2bf(b.x); r[5] = f2bf(b.y); r[6] = f2bf(b.z); r[7] = f2bf(b.w);
  *(u16x8*)(dst + (long)i * 8) = r;
}

// all four weight matrices in one launch
__global__ __launch_bounds__(256) void cvt_w_kernel(const float* __restrict__ wq,
                                                    const float* __restrict__ wk,
                                                    const float* __restrict__ wv,
                                                    const float* __restrict__ wo,
                                                    u16* __restrict__ wqkv,
                                                    u16* __restrict__ wobf) {
  int i = blockIdx.x * 256 + threadIdx.x;
  int seg = i >> 19;
  int r8 = i & 524287;
  const float* s = (seg == 0) ? wq : (seg == 1) ? wk : (seg == 2) ? wv : wo;
  u16* d = (seg == 3) ? wobf : (wqkv + (long)seg * 4194304);
  const float4* s4 = (const float4*)s;
  float4 a = s4[r8 * 2];
  float4 b = s4[r8 * 2 + 1];
  u16x8 r;
  r[0] = f2bf(a.x); r[1] = f2bf(a.y); r[2] = f2bf(a.z); r[3] = f2bf(a.w);
  r[4] = f2bf(b.x); r[5] = f2bf(b.y); r[6] = f2bf(b.z); r[7] = f2bf(b.w);
  *(u16x8*)(d + (long)r8 * 8) = r;
}

// ---------------- rope tables: [256][64] cos,sin ----------------
__global__ void rope_tables_kernel(float* __restrict__ cosT, float* __restrict__ sinT) {
  int i = blockIdx.x * 256 + threadIdx.x;  // 16384
  int t = i >> 6, d = i & 63;
  float inv = __expf(-(float)d * (9.210340371976184f / 64.0f));
  float a = (float)t * inv;
  cosT[i] = cosf(a);
  sinT[i] = sinf(a);
}

// ---------------- 256x256 8-phase GEMM  C = A * B^T ----------------
// 512 threads = 8 waves. Wave output = split sub-tiles: rows {mh*128+(wid>>2)*64+[0,64)},
// cols {nh*128+(wid&3)*32+[0,32)} -- every LDA_(mh)/LDB_(nh) confined to one stage-half.
// 1 stage/phase rotation, vmcnt(6) at p4/p8 (3 half-tiles in flight).
// MODE 0: f32 C[M][N] direct.  MODE 1: LDS-staged epilogue, fused RoPE+scale,
// coalesced u16x8 stores to Q/K/V [b][h][t][d].
#define MM(MH, NHh)                                                             \
  _Pragma("unroll") for (int ks = 0; ks < 2; ++ks)                              \
  _Pragma("unroll") for (int f = 0; f < 4; ++f)                                 \
  _Pragma("unroll") for (int fn = 0; fn < 2; ++fn)                              \
      acc[(MH)*4 + f][(NHh)*2 + fn] = __builtin_amdgcn_mfma_f32_16x16x32_bf16(  \
          fa[f][ks], fb[fn][ks], acc[(MH)*4 + f][(NHh)*2 + fn], 0, 0, 0);

template <int MODE>
__global__ __launch_bounds__(512, 2) void gemm256(const u16* __restrict__ A,
                                                  const u16* __restrict__ Bt,
                                                  float* __restrict__ Cf, u16* __restrict__ Qo,
                                                  u16* __restrict__ Ko, u16* __restrict__ Vo,
                                                  const float* __restrict__ cosT,
                                                  const float* __restrict__ sinT,
                                                  int M, int N, int K, int GX) {
  __shared__ u16 lds[65536];  // loop: [buf0.A][buf0.B][buf1.A][buf1.B]; epilogue: staging
  const int wg = blockIdx.x;  // plain order (XCD swizzle hurt L2 here: FETCH 176->320MB)
  const int bn = wg % GX, bm = wg / GX;
  const int tid = threadIdx.x, wid = tid >> 6, lane = tid & 63;
  const int lr = lane & 15, lg = lane >> 4;
  const int wrow = (wid >> 2) * 64;  // within each 128-row M half
  const int wcol = (wid & 3) * 32;   // within each 128-col N half
  const int NT = K >> 6;
  const u16* Ag = A + (long)(bm * 256) * K;
  const u16* Bg = Bt + (long)(bn * 256) * K;

  auto STG = [&](int matbase, int h, const u16* Gp, int kt) {
    if (kt > NT - 1) kt = NT - 1;
#pragma unroll
    for (int i_ = 0; i_ < 2; ++i_) {
      int s = i_ * 512 + tid;
      int r = h * 128 + (s >> 3);
      int cs = (s & 7) ^ (r & 7);
      gload_lds16(Gp + (long)r * K + kt * 64 + cs * 8, &lds[matbase + h * 8192 + s * 8]);
    }
  };

  bf16x8 fa[4][2], fb[2][2];
  auto LDA_ = [&](int base, int mh) {
#pragma unroll
    for (int f = 0; f < 4; ++f)
#pragma unroll
      for (int ks = 0; ks < 2; ++ks) {
        int r = wrow + f * 16 + lr;
        fa[f][ks] = *(const bf16x8*)&lds[base + mh * 8192 + r * 64 + (((ks * 4 + lg) ^ (r & 7))) * 8];
      }
  };
  auto LDB_ = [&](int base, int nh) {
#pragma unroll
    for (int fn = 0; fn < 2; ++fn)
#pragma unroll
      for (int ks = 0; ks < 2; ++ks) {
        int r = wcol + fn * 16 + lr;
        fb[fn][ks] = *(const bf16x8*)&lds[base + nh * 8192 + r * 64 + (((ks * 4 + lg) ^ (r & 7))) * 8];
      }
  };

  const f32x4 zero = {0.f, 0.f, 0.f, 0.f};
  f32x4 acc[8][4];
#pragma unroll
  for (int a = 0; a < 8; ++a)
#pragma unroll
    for (int b = 0; b < 4; ++b) acc[a][b] = zero;

  // prologue: t0 fully, t1 partial (A0,B1,A1); B0(t1) staged at first p1
  STG(0, 0, Ag, 0);
  STG(16384, 0, Bg, 0);
  STG(16384, 1, Bg, 0);
  STG(0, 1, Ag, 0);
  STG(32768, 0, Ag, 1);
  STG(49152, 1, Bg, 1);
  STG(32768, 1, Ag, 1);
  WV6();
  BAR();

  const int J = NT >> 1;
  for (int j = 0; j < J; ++j) {
    const int t1 = 2 * j + 1, tn0 = 2 * j + 2, tn1 = 2 * j + 3;
    // p1
    LDA_(0, 0); LDB_(16384, 0);
    STG(49152, 0, Bg, t1);
    BAR(); WL0();
    P1(); MM(0, 0) P0();
    BAR();
    // p2
    LDB_(16384, 1);
    STG(0, 0, Ag, tn0);
    BAR(); WL0();
    P1(); MM(0, 1) P0();
    BAR();
    // p3
    LDA_(0, 1);
    STG(16384, 1, Bg, tn0);
    BAR(); WL0();
    P1(); MM(1, 1) P0();
    BAR();
    // p4
    LDB_(16384, 0);
    STG(0, 1, Ag, tn0);
    BAR(); WL0();
    P1(); MM(1, 0) P0();
    WV6();
    BAR();
    // p5
    LDA_(32768, 0); LDB_(49152, 0);
    STG(16384, 0, Bg, tn0);
    BAR(); WL0();
    P1(); MM(0, 0) P0();
    BAR();
    // p6
    LDB_(49152, 1);
    STG(32768, 0, Ag, tn1);
    BAR(); WL0();
    P1(); MM(0, 1) P0();
    BAR();
    // p7
    LDA_(32768, 1);
    STG(49152, 1, Bg, tn1);
    BAR(); WL0();
    P1(); MM(1, 1) P0();
    BAR();
    // p8
    LDB_(49152, 0);
    STG(32768, 1, Ag, tn1);
    BAR(); WL0();
    P1(); MM(1, 0) P0();
    WV6();
    BAR();
  }
  WV0();  // drain in-flight LDS-DMA before LDS reuse / block exit
  BAR();

  if (MODE == 0) {
    // f32 direct: 16 lanes write 64B contiguous (full-line, no RMW)
#pragma unroll
    for (int am = 0; am < 8; ++am)
#pragma unroll
      for (int an = 0; an < 4; ++an)
#pragma unroll
        for (int r = 0; r < 4; ++r) {
          int m = bm * 256 + (am >> 2) * 128 + wrow + (am & 3) * 16 + lg * 4 + r;
          int n = bn * 256 + (an >> 1) * 128 + wcol + (an & 1) * 16 + lr;
          Cf[(long)m * N + n] = acc[am][an][r];
        }
  } else {
    // LDS-staged epilogue with fused RoPE. Tile n-range = one matrix (mat = bn>>3),
    // 2 heads. Two half-passes of 128 rows; LDS stride 272 u16 (16B-aligned rows,
    // lg-rows 4 apart -> +8 banks -> conflict-free writes).
    const int mat = bn >> 3;
    u16* dst = (mat == 0) ? Qo : ((mat == 1) ? Ko : Vo);
    const float qsc = (mat == 0) ? 0.08838834764831845f : 1.0f;
#pragma unroll
    for (int mh = 0; mh < 2; ++mh) {
      if (mh) BAR();
#pragma unroll
      for (int a4 = 0; a4 < 4; ++a4)
#pragma unroll
        for (int an = 0; an < 4; ++an)
#pragma unroll
          for (int r = 0; r < 4; ++r) {
            int rowl = wrow + a4 * 16 + lg * 4 + r;
            int col = (an >> 1) * 128 + wcol + (an & 1) * 16 + lr;
            lds[rowl * 272 + col] = f2bf(acc[mh * 4 + a4][an][r]);
          }
      BAR();
#pragma unroll
      for (int it = 0; it < 8; ++it) {
        int task = it * 512 + tid;
        int tl = task >> 5, c8 = task & 31;
        int hp = c8 >> 4, d0 = (c8 & 15) * 8;
        int t = mh * 128 + tl;
        int head = (bn * 2 + hp) & 15;
        u16x8 v1 = *(const u16x8*)&lds[tl * 272 + hp * 128 + d0];
        u16x8 o;
        if (mat < 2) {
          int dpart = (d0 < 64) ? (d0 + 64) : (d0 - 64);
          u16x8 v2 = *(const u16x8*)&lds[tl * 272 + hp * 128 + dpart];
          int dm = d0 & 63;
          float4 c0 = *(const float4*)(cosT + t * 64 + dm);
          float4 c1 = *(const float4*)(cosT + t * 64 + dm + 4);
          float4 s0 = *(const float4*)(sinT + t * 64 + dm);
          float4 s1 = *(const float4*)(sinT + t * 64 + dm + 4);
          float cc[8] = {c0.x, c0.y, c0.z, c0.w, c1.x, c1.y, c1.z, c1.w};
          float ss[8] = {s0.x, s0.y, s0.z, s0.w, s1.x, s1.y, s1.z, s1.w};
          float sgn = (d0 < 64) ? -1.f : 1.f;
#pragma unroll
          for (int j = 0; j < 8; ++j)
            o[j] = f2bf((bf2f(v1[j]) * cc[j] + sgn * bf2f(v2[j]) * ss[j]) * qsc);
        } else {
          o = v1;
        }
        *(u16x8*)(dst + (((long)(bm * NH + head)) * TT + t) * HD + d0) = o;
      }
    }
  }
}

// ---------------- fused causal attention ----------------
__global__ __launch_bounds__(256, 2) void attn_kernel(const u16* __restrict__ Qb,
                                                      const u16* __restrict__ Kb,
                                                      const u16* __restrict__ Vb,
                                                      u16* __restrict__ Ob) {
  __shared__ u16 Ks[64][136];
  __shared__ u16 Vt[128][72];
  __shared__ u16 Ps[4][32][72];
  const int bid = blockIdx.x;
  const int qb = bid & 1, h = (bid >> 1) & 15, b = bid >> 5;
  const int tid = threadIdx.x, wid = tid >> 6, lane = tid & 63;
  const int lr = lane & 15, lg = lane >> 4;
  const u16* qh = Qb + ((long)(b * NH + h)) * TT * HD;
  const u16* kh = Kb + ((long)(b * NH + h)) * TT * HD;
  const u16* vh = Vb + ((long)(b * NH + h)) * TT * HD;
  const int q0 = qb * 128 + wid * 32;

  bf16x8 qf[2][4];
#pragma unroll
  for (int fq = 0; fq < 2; ++fq)
#pragma unroll
    for (int ds = 0; ds < 4; ++ds)
      qf[fq][ds] = *(const bf16x8*)(qh + (long)(q0 + fq * 16 + lr) * HD + ds * 32 + lg * 8);

  const f32x4 zero = {0.f, 0.f, 0.f, 0.f};
  f32x4 oacc[2][8];
#pragma unroll
  for (int fq = 0; fq < 2; ++fq)
#pragma unroll
    for (int fd = 0; fd < 8; ++fd) oacc[fq][fd] = zero;
  float mrow[2][4], lrow[2][4];
#pragma unroll
  for (int fq = 0; fq < 2; ++fq)
#pragma unroll
    for (int r = 0; r < 4; ++r) { mrow[fq][r] = -1e30f; lrow[fq][r] = 0.f; }

  const int nch = (qb == 0) ? 2 : 4;
  for (int kc = 0; kc < nch; ++kc) {
    __syncthreads();
#pragma unroll
    for (int it = 0; it < 4; ++it) {
      int task = it * 256 + tid;
      int r = task >> 4, sg = task & 15;
      u16x8 v = *(const u16x8*)(kh + (long)(kc * 64 + r) * HD + sg * 8);
      *(u16x8*)(&Ks[r][sg * 8]) = v;
    }
#pragma unroll
    for (int it = 0; it < 4; ++it) {
      int task = it * 256 + tid;
      int r = task >> 4, d0 = (task & 15) * 8;
      u16x8 v = *(const u16x8*)(vh + (long)(kc * 64 + r) * HD + d0);
#pragma unroll
      for (int j = 0; j < 8; ++j) Vt[d0 + j][r] = v[j];
    }
    __syncthreads();

    f32x4 sacc[2][4];
#pragma unroll
    for (int fq = 0; fq < 2; ++fq)
#pragma unroll
      for (int fk = 0; fk < 4; ++fk) sacc[fq][fk] = zero;
#pragma unroll
    for (int ds = 0; ds < 4; ++ds) {
      bf16x8 kf[4];
#pragma unroll
      for (int fk = 0; fk < 4; ++fk)
        kf[fk] = *(const bf16x8*)(&Ks[fk * 16 + lr][ds * 32 + lg * 8]);
#pragma unroll
      for (int fq = 0; fq < 2; ++fq)
#pragma unroll
        for (int fk = 0; fk < 4; ++fk)
          sacc[fq][fk] =
              __builtin_amdgcn_mfma_f32_16x16x32_bf16(qf[fq][ds], kf[fk], sacc[fq][fk], 0, 0, 0);
    }

#pragma unroll
    for (int fq = 0; fq < 2; ++fq) {
      float mnew[4], alpha[4], psum[4];
#pragma unroll
      for (int r = 0; r < 4; ++r) {
        int qrow = q0 + fq * 16 + lg * 4 + r;
        float cmax = -1e30f;
#pragma unroll
        for (int fk = 0; fk < 4; ++fk) {
          int kcol = kc * 64 + fk * 16 + lr;
          float s = sacc[fq][fk][r];
          if (kcol > qrow) s = -1e30f;
          sacc[fq][fk][r] = s;
          cmax = fmaxf(cmax, s);
        }
#pragma unroll
        for (int off = 1; off < 16; off <<= 1) cmax = fmaxf(cmax, __shfl_xor(cmax, off));
        mnew[r] = fmaxf(mrow[fq][r], cmax);
        alpha[r] = __expf(mrow[fq][r] - mnew[r]);
        mrow[fq][r] = mnew[r];
        psum[r] = 0.f;
      }
#pragma unroll
      for (int fk = 0; fk < 4; ++fk)
#pragma unroll
        for (int r = 0; r < 4; ++r) {
          float p = __expf(sacc[fq][fk][r] - mnew[r]);
          psum[r] += p;
          Ps[wid][fq * 16 + lg * 4 + r][fk * 16 + lr] = f2bf(p);
        }
#pragma unroll
      for (int r = 0; r < 4; ++r) {
        float ps = psum[r];
#pragma unroll
        for (int off = 1; off < 16; off <<= 1) ps += __shfl_xor(ps, off);
        lrow[fq][r] = lrow[fq][r] * alpha[r] + ps;
#pragma unroll
        for (int fd = 0; fd < 8; ++fd) oacc[fq][fd][r] *= alpha[r];
      }
    }

#pragma unroll
    for (int ks = 0; ks < 2; ++ks) {
      bf16x8 pf0 = *(const bf16x8*)(&Ps[wid][lr][ks * 32 + lg * 8]);
      bf16x8 pf1 = *(const bf16x8*)(&Ps[wid][16 + lr][ks * 32 + lg * 8]);
#pragma unroll
      for (int fd = 0; fd < 8; ++fd) {
        bf16x8 vf = *(const bf16x8*)(&Vt[fd * 16 + lr][ks * 32 + lg * 8]);
        oacc[0][fd] = __builtin_amdgcn_mfma_f32_16x16x32_bf16(pf0, vf, oacc[0][fd], 0, 0, 0);
        oacc[1][fd] = __builtin_amdgcn_mfma_f32_16x16x32_bf16(pf1, vf, oacc[1][fd], 0, 0, 0);
      }
    }
  }

#pragma unroll
  for (int fq = 0; fq < 2; ++fq)
#pragma unroll
    for (int r = 0; r < 4; ++r) {
      float inv = 1.0f / lrow[fq][r];
      int t = q0 + fq * 16 + lg * 4 + r;
      u16* od = Ob + ((long)(b * TT + t)) * CDIM + h * HD;
#pragma unroll
      for (int fd = 0; fd < 8; ++fd) od[fd * 16 + lr] = f2bf(oacc[fq][fd][r] * inv);
    }
}

extern "C" void kernel_launch(void* const* d_in, const int* in_sizes, int n_in, void* d_out,
                              int out_size, void* d_ws, size_t ws_size, hipStream_t stream) {
  const float* x = (const float*)d_in[0];
  const float* wq = (const float*)d_in[2];
  const float* wk = (const float*)d_in[3];
  const float* wv = (const float*)d_in[4];
  const float* wo = (const float*)d_in[5];

  char* ws = (char*)d_ws;
  u16* xbf = (u16*)(ws);                   // 32 MB; later reused as attn-out [b][t][c]
  u16* wqkv = (u16*)(ws + 33554432);       // 24 MB  [6144][2048]
  u16* wobf = (u16*)(ws + 58720256);       // 8 MB
  u16* qbf = (u16*)(ws + 67108864);        // 32 MB  [b][h][t][d]
  u16* kbf = (u16*)(ws + 100663296);       // 32 MB
  u16* vbf = (u16*)(ws + 134217728);       // 32 MB
  float* cosT = (float*)(ws + 167772160);  // 64 KB
  float* sinT = (float*)(ws + 167837696);  // 64 KB

  cvt_bf16_kernel<<<8192, 256, 0, stream>>>(x, xbf, 2097152);
  cvt_w_kernel<<<8192, 256, 0, stream>>>(wq, wk, wv, wo, wqkv, wobf);
  rope_tables_kernel<<<64, 256, 0, stream>>>(cosT, sinT);

  gemm256<1><<<768, 512, 0, stream>>>(xbf, wqkv, nullptr, qbf, kbf, vbf, cosT, sinT, 8192, 6144,
                                      2048, 24);
  attn_kernel<<<1024, 256, 0, stream>>>(qbf, kbf, vbf, xbf);
  gemm256<0><<<256, 512, 0, stream>>>(xbf, wobf, (float*)d_out, nullptr, nullptr, nullptr, nullptr,
                                      nullptr, 8192, 2048, 2048, 8);
}

// Round 7
// 346.603 us; speedup vs baseline: 1.0704x; 1.0222x over previous
//
#include <hip/hip_runtime.h>

typedef unsigned short u16;
typedef unsigned int u32;
typedef __attribute__((ext_vector_type(4))) float f32x4;
typedef __attribute__((ext_vector_type(8))) short bf16x8;
typedef __attribute__((ext_vector_type(4))) unsigned short u16x4;
typedef __attribute__((ext_vector_type(8))) unsigned short u16x8;

#define NH 16
#define HD 128
#define TT 256
#define CDIM 2048

__device__ __forceinline__ u16 f2bf(float f) {
  u32 u = __float_as_uint(f);
  u = (u + 0x7fffu + ((u >> 16) & 1u)) >> 16;
  return (u16)u;
}
__device__ __forceinline__ float bf2f(u16 h) {
  return __uint_as_float(((u32)h) << 16);
}
__device__ __forceinline__ void gload_lds16(const u16* g, u16* l) {
  __builtin_amdgcn_global_load_lds((__attribute__((address_space(1))) void*)g,
                                   (__attribute__((address_space(3))) void*)l, 16, 0, 0);
}

#define BAR() __builtin_amdgcn_s_barrier()
#define SCB() __builtin_amdgcn_sched_barrier(0)
#define WL0()                                          \
  {                                                    \
    asm volatile("s_waitcnt lgkmcnt(0)" ::: "memory"); \
    SCB();                                             \
  }
#define WV8()                                         \
  {                                                   \
    asm volatile("s_waitcnt vmcnt(8)" ::: "memory");  \
    SCB();                                            \
  }
#define WVL0()                                                   \
  {                                                              \
    asm volatile("s_waitcnt vmcnt(0) lgkmcnt(0)" ::: "memory");  \
    SCB();                                                       \
  }
#define P1() __builtin_amdgcn_s_setprio(1)
#define P0() __builtin_amdgcn_s_setprio(0)

// ---------------- convert f32 -> bf16, 8 elems/thread ----------------
__global__ __launch_bounds__(256) void cvt_bf16_kernel(const float* __restrict__ src,
                                                       u16* __restrict__ dst, int n8) {
  int i = blockIdx.x * 256 + threadIdx.x;
  if (i >= n8) return;
  const float4* s4 = (const float4*)src;
  float4 a = s4[i * 2];
  float4 b = s4[i * 2 + 1];
  u16x8 r;
  r[0] = f2bf(a.x); r[1] = f2bf(a.y); r[2] = f2bf(a.z); r[3] = f2bf(a.w);
  r[4] = f2bf(b.x); r[5] = f2bf(b.y); r[6] = f2bf(b.z); r[7] = f2bf(b.w);
  *(u16x8*)(dst + (long)i * 8) = r;
}

// all four weight matrices in one launch
__global__ __launch_bounds__(256) void cvt_w_kernel(const float* __restrict__ wq,
                                                    const float* __restrict__ wk,
                                                    const float* __restrict__ wv,
                                                    const float* __restrict__ wo,
                                                    u16* __restrict__ wqkv,
                                                    u16* __restrict__ wobf) {
  int i = blockIdx.x * 256 + threadIdx.x;
  int seg = i >> 19;
  int r8 = i & 524287;
  const float* s = (seg == 0) ? wq : (seg == 1) ? wk : (seg == 2) ? wv : wo;
  u16* d = (seg == 3) ? wobf : (wqkv + (long)seg * 4194304);
  const float4* s4 = (const float4*)s;
  float4 a = s4[r8 * 2];
  float4 b = s4[r8 * 2 + 1];
  u16x8 r;
  r[0] = f2bf(a.x); r[1] = f2bf(a.y); r[2] = f2bf(a.z); r[3] = f2bf(a.w);
  r[4] = f2bf(b.x); r[5] = f2bf(b.y); r[6] = f2bf(b.z); r[7] = f2bf(b.w);
  *(u16x8*)(d + (long)r8 * 8) = r;
}

// ---------------- rope tables: [256][64] cos,sin ----------------
__global__ void rope_tables_kernel(float* __restrict__ cosT, float* __restrict__ sinT) {
  int i = blockIdx.x * 256 + threadIdx.x;  // 16384
  int t = i >> 6, d = i & 63;
  float inv = __expf(-(float)d * (9.210340371976184f / 64.0f));
  float a = (float)t * inv;
  cosT[i] = cosf(a);
  sinT[i] = sinf(a);
}

// ---------------- 256x256 8-phase GEMM  C = A * B^T ----------------
// 512 threads = 8 waves, per-wave output 64 rows x 128 cols (4M x 2N).
// Per K-tile: A read ONCE at q1 (fa held all 4 phases), B in 4 quarter-phases
// -- zero redundant LDS reads. Stage unit = 64x64 (1 gload/thread).
// RACE RULE (R6 post-mortem): every LDS read (LDA_/LDB_) must follow a
// {own-wave vmcnt wait -> s_barrier} pair covering its unit's staging DMAs --
// own-wave WV8 alone does NOT cover other waves' 1/8 contributions.
// Rotation: q1->B*b(t+1), q2/q3->A(t+2), q4->B*a(t+2); vmcnt(8) at q2/q4 ends.
#define MMQ(Q)                                                      \
  _Pragma("unroll") for (int ks = 0; ks < 2; ++ks)                  \
  _Pragma("unroll") for (int f = 0; f < 4; ++f)                     \
  _Pragma("unroll") for (int fn = 0; fn < 2; ++fn)                  \
      acc[f][(Q)*2 + fn] = __builtin_amdgcn_mfma_f32_16x16x32_bf16( \
          fa[f][ks], fb[fn][ks], acc[f][(Q)*2 + fn], 0, 0, 0);

template <int MODE>
__global__ __launch_bounds__(512, 2) void gemm256(const u16* __restrict__ A,
                                                  const u16* __restrict__ Bt,
                                                  float* __restrict__ Cf, u16* __restrict__ Qo,
                                                  u16* __restrict__ Ko, u16* __restrict__ Vo,
                                                  const float* __restrict__ cosT,
                                                  const float* __restrict__ sinT,
                                                  int M, int N, int K, int GX) {
  __shared__ u16 lds[65536];  // [bufA 16K][bufB 16K][bufA' 16K][bufB' 16K] u16
  const int wg = blockIdx.x;
  const int bn = wg % GX, bm = wg / GX;
  const int tid = threadIdx.x, wid = tid >> 6, lane = tid & 63;
  const int lr = lane & 15, lg = lane >> 4;
  const int wr = (wid >> 1) * 64;  // wave row base in [0,256)
  const int wch = wid & 1;         // wave B-half
  const int NT = K >> 6;
  const u16* Ag = A + (long)(bm * 256) * K;
  const u16* Bg = Bt + (long)(bn * 256) * K;

  // stage one 64x64 unit (8KB): 1 gload/thread; dest linear, src col pre-swizzled
  auto STGU = [&](int ldso, const u16* grow, int kt) {
    if (kt > NT - 1) kt = NT - 1;
    int r = tid >> 3, cs = (tid & 7) ^ (r & 7);
    gload_lds16(grow + (long)r * K + kt * 64 + cs * 8, &lds[ldso + tid * 8]);
  };

  bf16x8 fa[4][2], fb[2][2];
  auto LDA_ = [&](int bufo) {  // load fa (whole K-tile of this wave's 64 rows)
#pragma unroll
    for (int f = 0; f < 4; ++f) {
      int rg = wr + f * 16 + lr;
      int h = rg >> 7, rl = rg & 127;
#pragma unroll
      for (int ks = 0; ks < 2; ++ks)
        fa[f][ks] = *(const bf16x8*)&lds[bufo + h * 8192 + rl * 64 + (((ks * 4 + lg) ^ (rl & 7))) * 8];
    }
  };
  auto LDB_ = [&](int bufc, int q) {  // load one 32-row B quarter
#pragma unroll
    for (int fn = 0; fn < 2; ++fn) {
      int rl = q * 32 + fn * 16 + lr;
#pragma unroll
      for (int ks = 0; ks < 2; ++ks)
        fb[fn][ks] = *(const bf16x8*)&lds[bufc + 16384 + wch * 8192 + rl * 64 +
                                          (((ks * 4 + lg) ^ (rl & 7))) * 8];
    }
  };

  const f32x4 zero = {0.f, 0.f, 0.f, 0.f};
  f32x4 acc[4][8];
#pragma unroll
  for (int a = 0; a < 4; ++a)
#pragma unroll
    for (int b = 0; b < 8; ++b) acc[a][b] = zero;

  // prologue: A(0)x4, Ba(0)x2 [drained by WV8]; Bb(0)x2, A(1)x4, Ba(1)x2 [in flight]
  STGU(0, Ag, 0);
  STGU(4096, Ag + (long)64 * K, 0);
  STGU(8192, Ag + (long)128 * K, 0);
  STGU(12288, Ag + (long)192 * K, 0);
  STGU(16384, Bg, 0);
  STGU(24576, Bg + (long)128 * K, 0);
  STGU(20480, Bg + (long)64 * K, 0);
  STGU(28672, Bg + (long)192 * K, 0);
  STGU(32768, Ag, 1);
  STGU(36864, Ag + (long)64 * K, 1);
  STGU(40960, Ag + (long)128 * K, 1);
  STGU(45056, Ag + (long)192 * K, 1);
  STGU(49152, Bg, 1);
  STGU(57344, Bg + (long)128 * K, 1);
  WV8();
  BAR();  // all waves' A(0)+Ba(0) landed -> q1 may read

#define TILE(CB, OB, T1, T2)                      \
  LDA_(CB);                                       \
  LDB_(CB, 0);                                    \
  STGU((OB) + 20480, Bg + (long)64 * K, T1);      \
  STGU((OB) + 28672, Bg + (long)192 * K, T1);     \
  BAR(); WL0();                                   \
  P1(); MMQ(0) P0();                              \
  BAR();                                          \
  LDB_(CB, 1);                                    \
  STGU((CB) + 0, Ag, T2);                         \
  STGU((CB) + 4096, Ag + (long)64 * K, T2);       \
  BAR(); WL0();                                   \
  P1(); MMQ(1) P0();                              \
  WV8();                                          \
  BAR();                                          \
  LDB_(CB, 2);                                    \
  STGU((CB) + 8192, Ag + (long)128 * K, T2);      \
  STGU((CB) + 12288, Ag + (long)192 * K, T2);     \
  BAR(); WL0();                                   \
  P1(); MMQ(2) P0();                              \
  BAR();                                          \
  LDB_(CB, 3);                                    \
  STGU((CB) + 16384, Bg, T2);                     \
  STGU((CB) + 24576, Bg + (long)128 * K, T2);     \
  BAR(); WL0();                                   \
  P1(); MMQ(3) P0();                              \
  WV8();                                          \
  BAR();

  const int J = NT >> 1;
  for (int j = 0; j < J; ++j) {
    const int t1 = 2 * j + 1, t2 = 2 * j + 2, t3 = 2 * j + 3;
    TILE(0, 32768, t1, t2)
    TILE(32768, 0, t2, t3)
  }
  WVL0();  // drain remaining DMA before LDS reuse / block exit
  BAR();

  if (MODE == 0) {
#pragma unroll
    for (int f = 0; f < 4; ++f)
#pragma unroll
      for (int j8 = 0; j8 < 8; ++j8)
#pragma unroll
        for (int r = 0; r < 4; ++r) {
          int m = bm * 256 + wr + f * 16 + lg * 4 + r;
          int n = bn * 256 + wch * 128 + (j8 >> 1) * 32 + (j8 & 1) * 16 + lr;
          Cf[(long)m * N + n] = acc[f][j8][r];
        }
  } else {
    // LDS-staged epilogue with fused RoPE. Tile = one matrix (mat = bn>>3), 2 heads.
    // Two half-passes of 128 rows; LDS stride 272 u16.
    const int mat = bn >> 3;
    u16* dst = (mat == 0) ? Qo : ((mat == 1) ? Ko : Vo);
    const float qsc = (mat == 0) ? 0.08838834764831845f : 1.0f;
#pragma unroll
    for (int mh = 0; mh < 2; ++mh) {
      if (mh) BAR();
      if ((wid >> 2) == mh) {
#pragma unroll
        for (int f = 0; f < 4; ++f)
#pragma unroll
          for (int j8 = 0; j8 < 8; ++j8)
#pragma unroll
            for (int r = 0; r < 4; ++r) {
              int rowl = ((wid >> 1) & 1) * 64 + f * 16 + lg * 4 + r;
              int col = wch * 128 + (j8 >> 1) * 32 + (j8 & 1) * 16 + lr;
              lds[rowl * 272 + col] = f2bf(acc[f][j8][r]);
            }
      }
      BAR();
#pragma unroll
      for (int it = 0; it < 8; ++it) {
        int task = it * 512 + tid;
        int tl = task >> 5, c8 = task & 31;
        int hp = c8 >> 4, d0 = (c8 & 15) * 8;
        int t = mh * 128 + tl;
        int head = (bn * 2 + hp) & 15;
        u16x8 v1 = *(const u16x8*)&lds[tl * 272 + hp * 128 + d0];
        u16x8 o;
        if (mat < 2) {
          int dpart = (d0 < 64) ? (d0 + 64) : (d0 - 64);
          u16x8 v2 = *(const u16x8*)&lds[tl * 272 + hp * 128 + dpart];
          int dm = d0 & 63;
          float4 c0 = *(const float4*)(cosT + t * 64 + dm);
          float4 c1 = *(const float4*)(cosT + t * 64 + dm + 4);
          float4 s0 = *(const float4*)(sinT + t * 64 + dm);
          float4 s1 = *(const float4*)(sinT + t * 64 + dm + 4);
          float cc[8] = {c0.x, c0.y, c0.z, c0.w, c1.x, c1.y, c1.z, c1.w};
          float ss[8] = {s0.x, s0.y, s0.z, s0.w, s1.x, s1.y, s1.z, s1.w};
          float sgn = (d0 < 64) ? -1.f : 1.f;
#pragma unroll
          for (int jj = 0; jj < 8; ++jj)
            o[jj] = f2bf((bf2f(v1[jj]) * cc[jj] + sgn * bf2f(v2[jj]) * ss[jj]) * qsc);
        } else {
          o = v1;
        }
        *(u16x8*)(dst + (((long)(bm * NH + head)) * TT + t) * HD + d0) = o;
      }
    }
  }
}

// ---------------- fused causal attention ----------------
__global__ __launch_bounds__(256, 2) void attn_kernel(const u16* __restrict__ Qb,
                                                      const u16* __restrict__ Kb,
                                                      const u16* __restrict__ Vb,
                                                      u16* __restrict__ Ob) {
  __shared__ u16 Ks[64][136];
  __shared__ u16 Vt[128][72];
  __shared__ u16 Ps[4][32][72];
  const int bid = blockIdx.x;
  const int qb = bid & 1, h = (bid >> 1) & 15, b = bid >> 5;
  const int tid = threadIdx.x, wid = tid >> 6, lane = tid & 63;
  const int lr = lane & 15, lg = lane >> 4;
  const u16* qh = Qb + ((long)(b * NH + h)) * TT * HD;
  const u16* kh = Kb + ((long)(b * NH + h)) * TT * HD;
  const u16* vh = Vb + ((long)(b * NH + h)) * TT * HD;
  const int q0 = qb * 128 + wid * 32;

  bf16x8 qf[2][4];
#pragma unroll
  for (int fq = 0; fq < 2; ++fq)
#pragma unroll
    for (int ds = 0; ds < 4; ++ds)
      qf[fq][ds] = *(const bf16x8*)(qh + (long)(q0 + fq * 16 + lr) * HD + ds * 32 + lg * 8);

  const f32x4 zero = {0.f, 0.f, 0.f, 0.f};
  f32x4 oacc[2][8];
#pragma unroll
  for (int fq = 0; fq < 2; ++fq)
#pragma unroll
    for (int fd = 0; fd < 8; ++fd) oacc[fq][fd] = zero;
  float mrow[2][4], lrow[2][4];
#pragma unroll
  for (int fq = 0; fq < 2; ++fq)
#pragma unroll
    for (int r = 0; r < 4; ++r) { mrow[fq][r] = -1e30f; lrow[fq][r] = 0.f; }

  const int nch = (qb == 0) ? 2 : 4;
  for (int kc = 0; kc < nch; ++kc) {
    __syncthreads();
#pragma unroll
    for (int it = 0; it < 4; ++it) {
      int task = it * 256 + tid;
      int r = task >> 4, sg = task & 15;
      u16x8 v = *(const u16x8*)(kh + (long)(kc * 64 + r) * HD + sg * 8);
      *(u16x8*)(&Ks[r][sg * 8]) = v;
    }
#pragma unroll
    for (int it = 0; it < 4; ++it) {
      int task = it * 256 + tid;
      int r = task >> 4, d0 = (task & 15) * 8;
      u16x8 v = *(const u16x8*)(vh + (long)(kc * 64 + r) * HD + d0);
#pragma unroll
      for (int j = 0; j < 8; ++j) Vt[d0 + j][r] = v[j];
    }
    __syncthreads();

    f32x4 sacc[2][4];
#pragma unroll
    for (int fq = 0; fq < 2; ++fq)
#pragma unroll
      for (int fk = 0; fk < 4; ++fk) sacc[fq][fk] = zero;
#pragma unroll
    for (int ds = 0; ds < 4; ++ds) {
      bf16x8 kf[4];
#pragma unroll
      for (int fk = 0; fk < 4; ++fk)
        kf[fk] = *(const bf16x8*)(&Ks[fk * 16 + lr][ds * 32 + lg * 8]);
#pragma unroll
      for (int fq = 0; fq < 2; ++fq)
#pragma unroll
        for (int fk = 0; fk < 4; ++fk)
          sacc[fq][fk] =
              __builtin_amdgcn_mfma_f32_16x16x32_bf16(qf[fq][ds], kf[fk], sacc[fq][fk], 0, 0, 0);
    }

#pragma unroll
    for (int fq = 0; fq < 2; ++fq) {
      float mnew[4], alpha[4], psum[4];
#pragma unroll
      for (int r = 0; r < 4; ++r) {
        int qrow = q0 + fq * 16 + lg * 4 + r;
        float cmax = -1e30f;
#pragma unroll
        for (int fk = 0; fk < 4; ++fk) {
          int kcol = kc * 64 + fk * 16 + lr;
          float s = sacc[fq][fk][r];
          if (kcol > qrow) s = -1e30f;
          sacc[fq][fk][r] = s;
          cmax = fmaxf(cmax, s);
        }
#pragma unroll
        for (int off = 1; off < 16; off <<= 1) cmax = fmaxf(cmax, __shfl_xor(cmax, off));
        mnew[r] = fmaxf(mrow[fq][r], cmax);
        alpha[r] = __expf(mrow[fq][r] - mnew[r]);
        mrow[fq][r] = mnew[r];
        psum[r] = 0.f;
      }
#pragma unroll
      for (int fk = 0; fk < 4; ++fk)
#pragma unroll
        for (int r = 0; r < 4; ++r) {
          float p = __expf(sacc[fq][fk][r] - mnew[r]);
          psum[r] += p;
          Ps[wid][fq * 16 + lg * 4 + r][fk * 16 + lr] = f2bf(p);
        }
#pragma unroll
      for (int r = 0; r < 4; ++r) {
        float ps = psum[r];
#pragma unroll
        for (int off = 1; off < 16; off <<= 1) ps += __shfl_xor(ps, off);
        lrow[fq][r] = lrow[fq][r] * alpha[r] + ps;
#pragma unroll
        for (int fd = 0; fd < 8; ++fd) oacc[fq][fd][r] *= alpha[r];
      }
    }

#pragma unroll
    for (int ks = 0; ks < 2; ++ks) {
      bf16x8 pf0 = *(const bf16x8*)(&Ps[wid][lr][ks * 32 + lg * 8]);
      bf16x8 pf1 = *(const bf16x8*)(&Ps[wid][16 + lr][ks * 32 + lg * 8]);
#pragma unroll
      for (int fd = 0; fd < 8; ++fd) {
        bf16x8 vf = *(const bf16x8*)(&Vt[fd * 16 + lr][ks * 32 + lg * 8]);
        oacc[0][fd] = __builtin_amdgcn_mfma_f32_16x16x32_bf16(pf0, vf, oacc[0][fd], 0, 0, 0);
        oacc[1][fd] = __builtin_amdgcn_mfma_f32_16x16x32_bf16(pf1, vf, oacc[1][fd], 0, 0, 0);
      }
    }
  }

#pragma unroll
  for (int fq = 0; fq < 2; ++fq)
#pragma unroll
    for (int r = 0; r < 4; ++r) {
      float inv = 1.0f / lrow[fq][r];
      int t = q0 + fq * 16 + lg * 4 + r;
      u16* od = Ob + ((long)(b * TT + t)) * CDIM + h * HD;
#pragma unroll
      for (int fd = 0; fd < 8; ++fd) od[fd * 16 + lr] = f2bf(oacc[fq][fd][r] * inv);
    }
}

extern "C" void kernel_launch(void* const* d_in, const int* in_sizes, int n_in, void* d_out,
                              int out_size, void* d_ws, size_t ws_size, hipStream_t stream) {
  const float* x = (const float*)d_in[0];
  const float* wq = (const float*)d_in[2];
  const float* wk = (const float*)d_in[3];
  const float* wv = (const float*)d_in[4];
  const float* wo = (const float*)d_in[5];

  char* ws = (char*)d_ws;
  u16* xbf = (u16*)(ws);                   // 32 MB; later reused as attn-out [b][t][c]
  u16* wqkv = (u16*)(ws + 33554432);       // 24 MB  [6144][2048]
  u16* wobf = (u16*)(ws + 58720256);       // 8 MB
  u16* qbf = (u16*)(ws + 67108864);        // 32 MB  [b][h][t][d]
  u16* kbf = (u16*)(ws + 100663296);       // 32 MB
  u16* vbf = (u16*)(ws + 134217728);       // 32 MB
  float* cosT = (float*)(ws + 167772160);  // 64 KB
  float* sinT = (float*)(ws + 167837696);  // 64 KB

  cvt_bf16_kernel<<<8192, 256, 0, stream>>>(x, xbf, 2097152);
  cvt_w_kernel<<<8192, 256, 0, stream>>>(wq, wk, wv, wo, wqkv, wobf);
  rope_tables_kernel<<<64, 256, 0, stream>>>(cosT, sinT);

  gemm256<1><<<768, 512, 0, stream>>>(xbf, wqkv, nullptr, qbf, kbf, vbf, cosT, sinT, 8192, 6144,
                                      2048, 24);
  attn_kernel<<<1024, 256, 0, stream>>>(qbf, kbf, vbf, xbf);
  gemm256<0><<<256, 512, 0, stream>>>(xbf, wobf, (float*)d_out, nullptr, nullptr, nullptr, nullptr,
                                      nullptr, 8192, 2048, 2048, 8);
}